// Round 5
// baseline (473.547 us; speedup 1.0000x reference)
//
#include <hip/hip_runtime.h>
#include <hip/hip_bf16.h>

// out[i] = 10 * min_j ||x_i - y_j||, x: 8192x96 f32, y: 65536x96 f32.
// sq = x2[i] + (y2[j] - 2*x.y): bf16 MFMA computes (y2 - 2*x.y) by pre-scaling
// train by -2 (exact in bf16) and preloading y2 as the MFMA C operand.
// R11: residency experiment. Model: per-SIMD matrix pipe = one 16x16x32 MFMA
//      per ~19.4cy (m06), so per wave per tile 48 MFMA = 932cy demand vs
//      ~6150cy measured tile period -> MfmaUtil ~= waves/SIMD * 15%. Measured
//      53% @ occupancy 33-40% fits exactly: the kernel is RESIDENCY-bound
//      (VALU/LDS fit in the 19cy inter-MFMA shadows; R6/R10 variants all
//      ~82-86us because none changed waves/SIMD).
//      -> grid 2048 (TSPLIT=64, 8 WG/CU offered), dbuf LDS 24.5KB (6 WG/CU
//      fit), __launch_bounds__(256,6). Compute body identical to R10.
//    - kept: global_load_lds DMA staging (R10: no scratch, WRITE 1MB),
//      2-phase dbuf pipeline w/ one barrier/tile, fragment-major LDS
//      (0 bank conflicts), XCD chunking, volatile bq loads, 4x3-deep chains.

typedef __attribute__((ext_vector_type(8))) short bf16x8;
typedef __attribute__((ext_vector_type(4))) float f32x4;

#define NQ 8192
#define NT 65536
#define KD 96
#define QB 256            // queries per WG: 4 waves x 64
#define TSPLIT 64         // train chunks; chunk t -> XCD t%8
#define TCHUNK (NT / TSPLIT)   // 1024 rows per WG
#define TTILE 64          // train rows per LDS tile
#define TILES (TCHUNK / TTILE) // 16
#define FRAG_USH 512      // ushorts per (tt,kb) fragment block (64 lanes x 8)

#define GLOAD_LDS16(gp, lp)                                                  \
  __builtin_amdgcn_global_load_lds(                                          \
      (const __attribute__((address_space(1))) unsigned int*)(gp),           \
      (__attribute__((address_space(3))) unsigned int*)(lp), 16, 0, 0)
#define GLOAD_LDS4(gp, lp)                                                   \
  __builtin_amdgcn_global_load_lds(                                          \
      (const __attribute__((address_space(1))) unsigned int*)(gp),           \
      (__attribute__((address_space(3))) unsigned int*)(lp), 4, 0, 0)

static __device__ __forceinline__ ushort f2bf(float f) {
  unsigned u = __float_as_uint(f);
  return (ushort)((u + 0x7fffu + ((u >> 16) & 1u)) >> 16);
}
static __device__ __forceinline__ unsigned pk2(float a, float b) {
  return (unsigned)f2bf(a) | ((unsigned)f2bf(b) << 16);
}

// Thread t owns float4s [6t, 6t+6) = one quarter-row (96B contiguous).
// Row norm = quad shuffle-reduce (xor 1, xor 2). No LDS, no barriers.
__global__ __launch_bounds__(256) void prep_kernel(
    const float* __restrict__ qf, const float* __restrict__ tf,
    ushort* __restrict__ qbf, ushort* __restrict__ tbf,
    float* __restrict__ x2, float* __restrict__ y2,
    float* __restrict__ outp)
{
  const int tid = threadIdx.x;
  const int b = blockIdx.x;
  const bool isq = b < (NQ / 64);
  const int rb = isq ? b : b - (NQ / 64);
  const float4* src = (const float4*)((isq ? qf : tf) + (size_t)rb * 64 * KD);
  uint2* dst = (uint2*)((isq ? qbf : tbf) + (size_t)rb * 64 * KD);
  const float scale = isq ? 1.0f : -2.0f;

  float s = 0.0f;
  #pragma unroll
  for (int i = 0; i < 6; ++i) {
    float4 v = src[tid * 6 + i];
    s += v.x * v.x + v.y * v.y + v.z * v.z + v.w * v.w;
    uint2 p; p.x = pk2(v.x * scale, v.y * scale); p.y = pk2(v.z * scale, v.w * scale);
    dst[tid * 6 + i] = p;
  }
  s += __shfl_xor(s, 1, 64);
  s += __shfl_xor(s, 2, 64);
  if ((tid & 3) == 0) {
    int row = rb * 64 + (tid >> 2);
    if (isq) { x2[row] = s; outp[row] = __uint_as_float(0x7f800000u); }
    else     { y2[row] = s; }
  }
}

__global__ __launch_bounds__(256, 6) void min_dist_kernel(
    const ushort* __restrict__ qbf, const ushort* __restrict__ tbf,
    const float* __restrict__ x2, const float* __restrict__ y2,
    float* __restrict__ outp)
{
  // fragment-major A tile, double-buffered: [buf][tt][kb] blocks of
  // 64 lanes x 16B; gload_lds dest = wave-uniform base + lane*16.
  __shared__ __align__(16) ushort ldsA[2][TTILE * KD];   // 24 KB
  __shared__ __align__(16) float ldsY[2][TTILE];         // 512 B

  const int tid  = threadIdx.x;
  const int w    = tid >> 6;
  const int lane = tid & 63;
  const int quad = lane >> 4;
  const int n    = lane & 15;
  const int tsplit = blockIdx.x & (TSPLIT - 1);   // -> XCD tsplit%8
  const int qblock = blockIdx.x / TSPLIT;
  const int qbase  = qblock * QB + w * 64;

  // B-operand (query) fragments: 4 col-tiles x 3 k-blocks = 48 VGPRs.
  // volatile: forbid the compiler from sinking these loads into the K-loop
  // (R4/R5: it did, VGPR_Count dropped below 48 and the kernel went TCP-bound)
  bf16x8 bq[4][3];
  #pragma unroll
  for (int ct = 0; ct < 4; ++ct) {
    const ushort* qp = qbf + (size_t)(qbase + ct * 16 + n) * KD + quad * 8;
    #pragma unroll
    for (int kb = 0; kb < 3; ++kb)
      bq[ct][kb] = *(const volatile bf16x8*)(qp + kb * 32);
  }

  // staging map: thread t's 16B chunk o = it*256+t; LDS lane-contiguous
  int goff[3], loff[3];
  #pragma unroll
  for (int it = 0; it < 3; ++it) {
    int o = it * 256 + tid;           // 16B chunk id 0..767
    int frag = o >> 6;                // tt*3+kb (wave-uniform)
    int tt = frag / 3, kb = frag - tt * 3;
    int l = o & 63;
    goff[it] = (tt * 16 + (l & 15)) * KD + kb * 32 + (l >> 4) * 8;  // ushort
    loff[it] = o * 8;                                                // ushort
  }

  const float INF = __uint_as_float(0x7f800000u);
  float m0 = INF, m1 = INF, m2 = INF, m3 = INF;

  const int trow0 = tsplit * TCHUNK;

  // prologue: DMA tile 0 into buffer 0
  {
    const ushort* g0 = tbf + (size_t)trow0 * KD;
    #pragma unroll
    for (int it = 0; it < 3; ++it)
      GLOAD_LDS16(g0 + goff[it], &ldsA[0][loff[it]]);
    if (w == 0)
      GLOAD_LDS4(y2 + trow0 + lane, &ldsY[0][lane]);
  }
  __syncthreads();   // drains vmcnt(0) + barrier

  int cur = 0;
  #pragma unroll 1
  for (int tile = 0; tile < TILES; ++tile) {
    // issue next tile's DMA into the other buffer; latency hides under MFMAs
    if (tile + 1 < TILES) {
      const int tb2 = trow0 + (tile + 1) * TTILE;
      const ushort* g2 = tbf + (size_t)tb2 * KD;
      #pragma unroll
      for (int it = 0; it < 3; ++it)
        GLOAD_LDS16(g2 + goff[it], &ldsA[cur ^ 1][loff[it]]);
      if (w == 0)
        GLOAD_LDS4(y2 + tb2 + lane, &ldsY[cur ^ 1][lane]);
    }

    #pragma unroll
    for (int tt = 0; tt < 4; ++tt) {
      const ushort* ap = &ldsA[cur][tt * 3 * FRAG_USH + lane * 8];
      bf16x8 a0 = *(const bf16x8*)(ap);
      bf16x8 a1 = *(const bf16x8*)(ap + FRAG_USH);
      bf16x8 a2 = *(const bf16x8*)(ap + 2 * FRAG_USH);
      f32x4 y2v = *(const f32x4*)&ldsY[cur][tt * 16 + quad * 4];

      f32x4 acc;
      acc = __builtin_amdgcn_mfma_f32_16x16x32_bf16(a0, bq[0][0], y2v, 0, 0, 0);
      acc = __builtin_amdgcn_mfma_f32_16x16x32_bf16(a1, bq[0][1], acc, 0, 0, 0);
      acc = __builtin_amdgcn_mfma_f32_16x16x32_bf16(a2, bq[0][2], acc, 0, 0, 0);
      m0 = fminf(fminf(fminf(acc[0], acc[1]), acc[2]), fminf(acc[3], m0));

      acc = __builtin_amdgcn_mfma_f32_16x16x32_bf16(a0, bq[1][0], y2v, 0, 0, 0);
      acc = __builtin_amdgcn_mfma_f32_16x16x32_bf16(a1, bq[1][1], acc, 0, 0, 0);
      acc = __builtin_amdgcn_mfma_f32_16x16x32_bf16(a2, bq[1][2], acc, 0, 0, 0);
      m1 = fminf(fminf(fminf(acc[0], acc[1]), acc[2]), fminf(acc[3], m1));

      acc = __builtin_amdgcn_mfma_f32_16x16x32_bf16(a0, bq[2][0], y2v, 0, 0, 0);
      acc = __builtin_amdgcn_mfma_f32_16x16x32_bf16(a1, bq[2][1], acc, 0, 0, 0);
      acc = __builtin_amdgcn_mfma_f32_16x16x32_bf16(a2, bq[2][2], acc, 0, 0, 0);
      m2 = fminf(fminf(fminf(acc[0], acc[1]), acc[2]), fminf(acc[3], m2));

      acc = __builtin_amdgcn_mfma_f32_16x16x32_bf16(a0, bq[3][0], y2v, 0, 0, 0);
      acc = __builtin_amdgcn_mfma_f32_16x16x32_bf16(a1, bq[3][1], acc, 0, 0, 0);
      acc = __builtin_amdgcn_mfma_f32_16x16x32_bf16(a2, bq[3][2], acc, 0, 0, 0);
      m3 = fminf(fminf(fminf(acc[0], acc[1]), acc[2]), fminf(acc[3], m3));
    }

    __syncthreads();   // waits vmcnt(0) (next-tile DMA) + lgkm, one barrier/tile
    cur ^= 1;
  }

  // fold across quads (lanes with equal n hold the same query columns)
  float m[4] = {m0, m1, m2, m3};
  #pragma unroll
  for (int ct = 0; ct < 4; ++ct) {
    m[ct] = fminf(m[ct], __shfl_xor(m[ct], 16, 64));
    m[ct] = fminf(m[ct], __shfl_xor(m[ct], 32, 64));
  }
  if (quad == 0) {
    #pragma unroll
    for (int ct = 0; ct < 4; ++ct) {
      int q = qbase + ct * 16 + n;
      float sq = fmaxf(x2[q] + m[ct], 0.0f);
      float val = sqrtf(sq) * 10.0f;
      atomicMin((unsigned int*)&outp[q], __float_as_uint(val));
    }
  }
}

extern "C" void kernel_launch(void* const* d_in, const int* in_sizes, int n_in,
                              void* d_out, int out_size, void* d_ws, size_t ws_size,
                              hipStream_t stream) {
  const float* qf = (const float*)d_in[0];   // mutation_dist 8192x96
  const float* tf = (const float*)d_in[1];   // train_data   65536x96
  float* outp = (float*)d_out;               // 8192 f32

  ushort* qbf = (ushort*)d_ws;                // 8192*96 bf16
  ushort* tbf = qbf + (size_t)NQ * KD;        // 65536*96 bf16, pre-scaled -2
  float* x2 = (float*)(tbf + (size_t)NT * KD);
  float* y2 = x2 + NQ;

  prep_kernel<<<(NQ + NT) / 64, 256, 0, stream>>>(qf, tf, qbf, tbf, x2, y2, outp);
  min_dist_kernel<<<(NQ / QB) * TSPLIT, 256, 0, stream>>>(qbf, tbf, x2, y2, outp);
}

// Round 6
// 147.432 us; speedup vs baseline: 3.2120x; 3.2120x over previous
//
#include <hip/hip_runtime.h>
#include <hip/hip_bf16.h>

// out[i] = 10 * min_j ||x_i - y_j||, x: 8192x96 f32, y: 65536x96 f32.
// sq = x2[i] + (y2[j] - 2*x.y): bf16 MFMA computes (y2 - 2*x.y) by pre-scaling
// train by -2 (exact in bf16) and preloading y2 as the MFMA C operand.
// R12: residency x2 at constant VGPR. R10 had 4 waves/SIMD (4 WG/CU x 4
//      waves / 4 SIMDs); pipe-demand math (4 x 48 MFMA x 19.4cy = 3725cy vs
//      6150cy period = 60%) matches measured MfmaUtil -> bubbles uncovered.
//      WG 256->512 threads (8 waves), QB=512: 4 WG/CU x 8 waves = 32
//      waves/CU = 8 waves/SIMD, same 52-VGPR budget, same LDS/WG, same grid
//      occupancy-per-CU, same per-wave body. LDS tile now broadcast to 8
//      waves (staging per query halves).
//      R11 lesson: launch_bounds squeeze below resident state = forced spill
//      (WRITE 194MB); (512,4) = 128-VGPR cap, compiler settles ~52.
//    - kept: global_load_lds DMA staging, 2-phase dbuf pipeline w/ one
//      barrier/tile, fragment-major LDS (0 bank conflicts), XCD chunking,
//      volatile bq loads, 4x3-deep MFMA chains.

typedef __attribute__((ext_vector_type(8))) short bf16x8;
typedef __attribute__((ext_vector_type(4))) float f32x4;

#define NQ 8192
#define NT 65536
#define KD 96
#define QB 512            // queries per WG: 8 waves x 64
#define TSPLIT 64         // train chunks; chunk t -> XCD t%8
#define TCHUNK (NT / TSPLIT)   // 1024 rows per WG
#define TTILE 64          // train rows per LDS tile
#define TILES (TCHUNK / TTILE) // 16
#define FRAG_USH 512      // ushorts per (tt,kb) fragment block (64 lanes x 8)

#define GLOAD_LDS16(gp, lp)                                                  \
  __builtin_amdgcn_global_load_lds(                                          \
      (const __attribute__((address_space(1))) unsigned int*)(gp),           \
      (__attribute__((address_space(3))) unsigned int*)(lp), 16, 0, 0)
#define GLOAD_LDS4(gp, lp)                                                   \
  __builtin_amdgcn_global_load_lds(                                          \
      (const __attribute__((address_space(1))) unsigned int*)(gp),           \
      (__attribute__((address_space(3))) unsigned int*)(lp), 4, 0, 0)

static __device__ __forceinline__ ushort f2bf(float f) {
  unsigned u = __float_as_uint(f);
  return (ushort)((u + 0x7fffu + ((u >> 16) & 1u)) >> 16);
}
static __device__ __forceinline__ unsigned pk2(float a, float b) {
  return (unsigned)f2bf(a) | ((unsigned)f2bf(b) << 16);
}

// Thread t owns float4s [6t, 6t+6) = one quarter-row (96B contiguous).
// Row norm = quad shuffle-reduce (xor 1, xor 2). No LDS, no barriers.
__global__ __launch_bounds__(256) void prep_kernel(
    const float* __restrict__ qf, const float* __restrict__ tf,
    ushort* __restrict__ qbf, ushort* __restrict__ tbf,
    float* __restrict__ x2, float* __restrict__ y2,
    float* __restrict__ outp)
{
  const int tid = threadIdx.x;
  const int b = blockIdx.x;
  const bool isq = b < (NQ / 64);
  const int rb = isq ? b : b - (NQ / 64);
  const float4* src = (const float4*)((isq ? qf : tf) + (size_t)rb * 64 * KD);
  uint2* dst = (uint2*)((isq ? qbf : tbf) + (size_t)rb * 64 * KD);
  const float scale = isq ? 1.0f : -2.0f;

  float s = 0.0f;
  #pragma unroll
  for (int i = 0; i < 6; ++i) {
    float4 v = src[tid * 6 + i];
    s += v.x * v.x + v.y * v.y + v.z * v.z + v.w * v.w;
    uint2 p; p.x = pk2(v.x * scale, v.y * scale); p.y = pk2(v.z * scale, v.w * scale);
    dst[tid * 6 + i] = p;
  }
  s += __shfl_xor(s, 1, 64);
  s += __shfl_xor(s, 2, 64);
  if ((tid & 3) == 0) {
    int row = rb * 64 + (tid >> 2);
    if (isq) { x2[row] = s; outp[row] = __uint_as_float(0x7f800000u); }
    else     { y2[row] = s; }
  }
}

__global__ __launch_bounds__(512, 4) void min_dist_kernel(
    const ushort* __restrict__ qbf, const ushort* __restrict__ tbf,
    const float* __restrict__ x2, const float* __restrict__ y2,
    float* __restrict__ outp)
{
  // fragment-major A tile, double-buffered: [buf][tt][kb] blocks of
  // 64 lanes x 16B; gload_lds dest = wave-uniform base + lane*16.
  __shared__ __align__(16) ushort ldsA[2][TTILE * KD];   // 24 KB
  __shared__ __align__(16) float ldsY[2][TTILE];         // 512 B

  const int tid  = threadIdx.x;
  const int w    = tid >> 6;      // 0..7
  const int lane = tid & 63;
  const int quad = lane >> 4;
  const int n    = lane & 15;
  const int tsplit = blockIdx.x & (TSPLIT - 1);   // -> XCD tsplit%8
  const int qblock = blockIdx.x / TSPLIT;
  const int qbase  = qblock * QB + w * 64;

  // B-operand (query) fragments: 4 col-tiles x 3 k-blocks = 48 VGPRs.
  // volatile: forbid the compiler from sinking these loads into the K-loop
  // (R4/R5: it did, VGPR_Count dropped below 48 and the kernel went TCP-bound)
  bf16x8 bq[4][3];
  #pragma unroll
  for (int ct = 0; ct < 4; ++ct) {
    const ushort* qp = qbf + (size_t)(qbase + ct * 16 + n) * KD + quad * 8;
    #pragma unroll
    for (int kb = 0; kb < 3; ++kb)
      bq[ct][kb] = *(const volatile bf16x8*)(qp + kb * 32);
  }

  // staging map: 768 16B chunks over 512 threads; chunk tid for all,
  // chunk 512+tid for tid<256 (waves 0-3: wave-uniform branch, DMA-legal)
  int goff0, loff0, goff1, loff1;
  {
    int o = tid;
    int frag = o >> 6, tt = frag / 3, kb = frag - tt * 3, l = o & 63;
    goff0 = (tt * 16 + (l & 15)) * KD + kb * 32 + (l >> 4) * 8;
    loff0 = o * 8;
    o = 512 + tid;
    frag = o >> 6; tt = frag / 3; kb = frag - tt * 3; l = o & 63;
    goff1 = (tt * 16 + (l & 15)) * KD + kb * 32 + (l >> 4) * 8;
    loff1 = o * 8;
  }

  const float INF = __uint_as_float(0x7f800000u);
  float m0 = INF, m1 = INF, m2 = INF, m3 = INF;

  const int trow0 = tsplit * TCHUNK;

  // prologue: DMA tile 0 into buffer 0
  {
    const ushort* g0 = tbf + (size_t)trow0 * KD;
    GLOAD_LDS16(g0 + goff0, &ldsA[0][loff0]);
    if (tid < 256)
      GLOAD_LDS16(g0 + goff1, &ldsA[0][loff1]);
    if (w == 0)
      GLOAD_LDS4(y2 + trow0 + lane, &ldsY[0][lane]);
  }
  __syncthreads();   // drains vmcnt(0) + barrier

  int cur = 0;
  #pragma unroll 1
  for (int tile = 0; tile < TILES; ++tile) {
    // issue next tile's DMA into the other buffer; latency hides under MFMAs
    if (tile + 1 < TILES) {
      const int tb2 = trow0 + (tile + 1) * TTILE;
      const ushort* g2 = tbf + (size_t)tb2 * KD;
      GLOAD_LDS16(g2 + goff0, &ldsA[cur ^ 1][loff0]);
      if (tid < 256)
        GLOAD_LDS16(g2 + goff1, &ldsA[cur ^ 1][loff1]);
      if (w == 0)
        GLOAD_LDS4(y2 + tb2 + lane, &ldsY[cur ^ 1][lane]);
    }

    #pragma unroll
    for (int tt = 0; tt < 4; ++tt) {
      const ushort* ap = &ldsA[cur][tt * 3 * FRAG_USH + lane * 8];
      bf16x8 a0 = *(const bf16x8*)(ap);
      bf16x8 a1 = *(const bf16x8*)(ap + FRAG_USH);
      bf16x8 a2 = *(const bf16x8*)(ap + 2 * FRAG_USH);
      f32x4 y2v = *(const f32x4*)&ldsY[cur][tt * 16 + quad * 4];

      f32x4 acc;
      acc = __builtin_amdgcn_mfma_f32_16x16x32_bf16(a0, bq[0][0], y2v, 0, 0, 0);
      acc = __builtin_amdgcn_mfma_f32_16x16x32_bf16(a1, bq[0][1], acc, 0, 0, 0);
      acc = __builtin_amdgcn_mfma_f32_16x16x32_bf16(a2, bq[0][2], acc, 0, 0, 0);
      m0 = fminf(fminf(fminf(acc[0], acc[1]), acc[2]), fminf(acc[3], m0));

      acc = __builtin_amdgcn_mfma_f32_16x16x32_bf16(a0, bq[1][0], y2v, 0, 0, 0);
      acc = __builtin_amdgcn_mfma_f32_16x16x32_bf16(a1, bq[1][1], acc, 0, 0, 0);
      acc = __builtin_amdgcn_mfma_f32_16x16x32_bf16(a2, bq[1][2], acc, 0, 0, 0);
      m1 = fminf(fminf(fminf(acc[0], acc[1]), acc[2]), fminf(acc[3], m1));

      acc = __builtin_amdgcn_mfma_f32_16x16x32_bf16(a0, bq[2][0], y2v, 0, 0, 0);
      acc = __builtin_amdgcn_mfma_f32_16x16x32_bf16(a1, bq[2][1], acc, 0, 0, 0);
      acc = __builtin_amdgcn_mfma_f32_16x16x32_bf16(a2, bq[2][2], acc, 0, 0, 0);
      m2 = fminf(fminf(fminf(acc[0], acc[1]), acc[2]), fminf(acc[3], m2));

      acc = __builtin_amdgcn_mfma_f32_16x16x32_bf16(a0, bq[3][0], y2v, 0, 0, 0);
      acc = __builtin_amdgcn_mfma_f32_16x16x32_bf16(a1, bq[3][1], acc, 0, 0, 0);
      acc = __builtin_amdgcn_mfma_f32_16x16x32_bf16(a2, bq[3][2], acc, 0, 0, 0);
      m3 = fminf(fminf(fminf(acc[0], acc[1]), acc[2]), fminf(acc[3], m3));
    }

    __syncthreads();   // waits vmcnt(0) (next-tile DMA) + lgkm, one barrier/tile
    cur ^= 1;
  }

  // fold across quads (lanes with equal n hold the same query columns)
  float m[4] = {m0, m1, m2, m3};
  #pragma unroll
  for (int ct = 0; ct < 4; ++ct) {
    m[ct] = fminf(m[ct], __shfl_xor(m[ct], 16, 64));
    m[ct] = fminf(m[ct], __shfl_xor(m[ct], 32, 64));
  }
  if (quad == 0) {
    #pragma unroll
    for (int ct = 0; ct < 4; ++ct) {
      int q = qbase + ct * 16 + n;
      float sq = fmaxf(x2[q] + m[ct], 0.0f);
      float val = sqrtf(sq) * 10.0f;
      atomicMin((unsigned int*)&outp[q], __float_as_uint(val));
    }
  }
}

extern "C" void kernel_launch(void* const* d_in, const int* in_sizes, int n_in,
                              void* d_out, int out_size, void* d_ws, size_t ws_size,
                              hipStream_t stream) {
  const float* qf = (const float*)d_in[0];   // mutation_dist 8192x96
  const float* tf = (const float*)d_in[1];   // train_data   65536x96
  float* outp = (float*)d_out;               // 8192 f32

  ushort* qbf = (ushort*)d_ws;                // 8192*96 bf16
  ushort* tbf = qbf + (size_t)NQ * KD;        // 65536*96 bf16, pre-scaled -2
  float* x2 = (float*)(tbf + (size_t)NT * KD);
  float* y2 = x2 + NQ;

  prep_kernel<<<(NQ + NT) / 64, 256, 0, stream>>>(qf, tf, qbf, tbf, x2, y2, outp);
  min_dist_kernel<<<(NQ / QB) * TSPLIT, 512, 0, stream>>>(qbf, tbf, x2, y2, outp);
}